// Round 6
// baseline (640.822 us; speedup 1.0000x reference)
//
#include <hip/hip_runtime.h>
#include <hip/hip_bf16.h>
#include <math.h>

// Transformer block, MI355X gfx950.
// R6: GEMM — 2x2 x mfma_32x32x16 (half the instr count, same traffic),
// __launch_bounds__(256,4) to fit 128 unified regs -> 4 blocks/CU,
// true XCD-aware mapping (ids = c mod 8 share B-tile), split-K=2 for the
// narrow-N GEMMs (proj, ff2) with 3-input resid_ln. Attention unchanged.

typedef __bf16 bf16_t;
typedef __bf16 bf16x8 __attribute__((ext_vector_type(8)));
typedef __bf16 bf16x4 __attribute__((ext_vector_type(4)));
typedef float f32x4 __attribute__((ext_vector_type(4)));
typedef float f32x16 __attribute__((ext_vector_type(16)));

#define HID   1024
#define NHEAD 16
#define HD    64
#define EXPD  4096
#define LSEQ  2048
#define BATCH 4
#define MROWS (BATCH * LSEQ)   // 8192

#if __has_builtin(__builtin_amdgcn_exp2f)
#define EXP2F __builtin_amdgcn_exp2f
#else
#define EXP2F exp2f
#endif

__device__ __forceinline__ void gld_lds16(const bf16_t* g, bf16_t* l) {
  __builtin_amdgcn_global_load_lds(
      (const __attribute__((address_space(1))) void*)g,
      (__attribute__((address_space(3))) void*)l, 16, 0, 0);
}

__device__ __forceinline__ void swap32(unsigned& a, unsigned& b) {
#if __has_builtin(__builtin_amdgcn_permlane32_swap)
  auto r = __builtin_amdgcn_permlane32_swap(a, b, false, false);
  a = r[0]; b = r[1];
#else
  bool hiL = ((threadIdx.x & 63) >= 32);
  unsigned pa = (unsigned)__shfl_xor((int)a, 32, 64);
  unsigned pb = (unsigned)__shfl_xor((int)b, 32, 64);
  unsigned na = hiL ? pb : a;
  unsigned nb = hiL ? b : pa;
  a = na; b = nb;
#endif
}

__device__ __forceinline__ unsigned pk_bf16(float lo, float hi) {
  bf16_t l = (bf16_t)lo, h = (bf16_t)hi;
  unsigned short ul, uh;
  __builtin_memcpy(&ul, &l, 2);
  __builtin_memcpy(&uh, &h, 2);
  return (unsigned)ul | ((unsigned)uh << 16);
}

// ---------------- convert f32 -> bf16 (x) ----------------
__global__ __launch_bounds__(256) void cvt_bf16(const float* __restrict__ in,
                                                bf16_t* __restrict__ out, int n4) {
  int i = blockIdx.x * 256 + threadIdx.x;
  if (i >= n4) return;
  float4 v = ((const float4*)in)[i];
  bf16x4 o;
  o[0] = (bf16_t)v.x; o[1] = (bf16_t)v.y; o[2] = (bf16_t)v.z; o[3] = (bf16_t)v.w;
  ((bf16x4*)out)[i] = o;
}

// ---------------- transpose + convert: W[K][N] f32 -> Wt[N][K] bf16 ----------------
__global__ __launch_bounds__(256) void transpose_cvt(const float* __restrict__ W,
                                                     bf16_t* __restrict__ Wt,
                                                     int K, int N) {
  __shared__ float tile[32][33];
  int n0 = blockIdx.x * 32, k0 = blockIdx.y * 32;
  int tx = threadIdx.x & 31, ty = threadIdx.x >> 5;
#pragma unroll
  for (int i = 0; i < 32; i += 8)
    tile[ty + i][tx] = W[(size_t)(k0 + ty + i) * N + n0 + tx];
  __syncthreads();
#pragma unroll
  for (int i = 0; i < 32; i += 8)
    Wt[(size_t)(n0 + ty + i) * K + k0 + tx] = (bf16_t)tile[tx][ty + i];
}

// ---------------- transpose V: qkvb V-part -> vT[b*16+h][d][l] bf16 ----------------
__global__ __launch_bounds__(256) void transpose_v(const bf16_t* __restrict__ qkvb,
                                                   bf16_t* __restrict__ vT) {
  __shared__ bf16_t tile[64][65];
  const int l0 = blockIdx.x * 64;
  const int bh = blockIdx.y;
  const int b = bh >> 4, h = bh & 15;
  const int tx = threadIdx.x & 63, ty = threadIdx.x >> 6;
  const bf16_t* src = qkvb + ((size_t)(b * LSEQ + l0)) * 3072 + 2048 + h * 64;
#pragma unroll
  for (int i = 0; i < 16; ++i) {
    int l = ty + 4 * i;
    tile[l][tx] = src[(size_t)l * 3072 + tx];
  }
  __syncthreads();
  bf16_t* dst = vT + ((size_t)bh * HD) * LSEQ + l0;
#pragma unroll
  for (int i = 0; i < 16; ++i) {
    int d = ty + 4 * i;
    dst[(size_t)d * LSEQ + tx] = tile[tx][d];
  }
}

// ---------------- GEMM: C[M][N] = A[M][K] @ Bt[N][K]^T + bias ----------------
// mode 0: bf16 out; mode 1: tanh-gelu bf16 out; mode 2: f32 out.
// lda = full K stride; Klen = this dispatch's K extent; blockIdx.z picks the
// K-slice (split-K): z=0 -> C (+bias), z=1 -> C1 (no bias).
// 2x2 grid of 32x32x16 MFMA per wave (64 AGPR); LDS chunk-XOR swizzle.
__global__ __launch_bounds__(256, 4) void gemm_bt(const bf16_t* __restrict__ A,
                                                  const bf16_t* __restrict__ Bt,
                                                  const float* __restrict__ bias,
                                                  void* __restrict__ C,
                                                  void* __restrict__ C1,
                                                  int M, int N, int Klen, int lda,
                                                  int mode) {
  __shared__ bf16_t As[128 * 32];
  __shared__ bf16_t Bs[128 * 32];
  // XCD-aware mapping: blocks with id = c (mod 8) live on the same XCD and
  // share one B-tile (bx) while sweeping all of M (by).
  const int nbx = gridDim.x, nby = gridDim.y;
  const int p = blockIdx.y * nbx + blockIdx.x;
  const int xcd = p & 7, s = p >> 3;
  const int by = s % nby, gx = s / nby;
  const int bx = xcd + 8 * gx;
  const int n0 = bx * 128, m0 = by * 128;

  const int t = threadIdx.x;
  const int lane = t & 63, w = t >> 6;
  const int wr = w >> 1, wc = w & 1;
  const int l32 = lane & 31, hi = lane >> 5;

  f32x16 acc[2][2];
#pragma unroll
  for (int mi = 0; mi < 2; ++mi)
#pragma unroll
    for (int nj = 0; nj < 2; ++nj)
#pragma unroll
      for (int e = 0; e < 16; ++e) acc[mi][nj][e] = 0.f;

  // loop-invariant per-lane DMA source offsets (swizzled k-chunk)
  const int r0 = t >> 2;
  const unsigned ksw = (((unsigned)t & 3u) ^ ((unsigned)(r0 >> 1) & 3u)) * 8u;
  const unsigned offL0 = (unsigned)r0 * (unsigned)lda + ksw;
  const unsigned offL1 = offL0 + 64u * (unsigned)lda;

  const bf16_t* aK = A + (size_t)m0 * lda + (size_t)blockIdx.z * Klen;
  const bf16_t* bK = Bt + (size_t)n0 * lda + (size_t)blockIdx.z * Klen;

  for (int k0 = 0; k0 < Klen; k0 += 32) {
    gld_lds16(aK + offL0, As + t * 8);
    gld_lds16(aK + offL1, As + (t + 256) * 8);
    gld_lds16(bK + offL0, Bs + t * 8);
    gld_lds16(bK + offL1, Bs + (t + 256) * 8);
    aK += 32;
    bK += 32;
    __syncthreads();
    bf16x8 af[2][2], bfr[2][2];  // [tile][k-half]
#pragma unroll
    for (int mi = 0; mi < 2; ++mi)
#pragma unroll
      for (int kh = 0; kh < 2; ++kh) {
        int row = wr * 64 + mi * 32 + l32;
        int y = kh * 2 + hi;
        af[mi][kh] = *(const bf16x8*)(As + (row * 4 + (y ^ ((row >> 1) & 3))) * 8);
      }
#pragma unroll
    for (int nj = 0; nj < 2; ++nj)
#pragma unroll
      for (int kh = 0; kh < 2; ++kh) {
        int row = wc * 64 + nj * 32 + l32;
        int y = kh * 2 + hi;
        bfr[nj][kh] = *(const bf16x8*)(Bs + (row * 4 + (y ^ ((row >> 1) & 3))) * 8);
      }
#pragma unroll
    for (int kh = 0; kh < 2; ++kh)
#pragma unroll
      for (int mi = 0; mi < 2; ++mi)
#pragma unroll
        for (int nj = 0; nj < 2; ++nj)
          acc[mi][nj] = __builtin_amdgcn_mfma_f32_32x32x16_bf16(
              af[mi][kh], bfr[nj][kh], acc[mi][nj], 0, 0, 0);
    __syncthreads();
  }

  // epilogue: C/D 32x32 layout: col = l32, row = (e&3) + 8*(e>>2) + 4*hi
  void* Cz = blockIdx.z ? C1 : C;
#pragma unroll
  for (int mi = 0; mi < 2; ++mi)
#pragma unroll
    for (int nj = 0; nj < 2; ++nj) {
      int col = n0 + wc * 64 + nj * 32 + l32;
      float bv = (blockIdx.z == 0) ? bias[col] : 0.f;
#pragma unroll
      for (int e = 0; e < 16; ++e) {
        int row = m0 + wr * 64 + mi * 32 + (e & 3) + 8 * (e >> 2) + 4 * hi;
        float v = acc[mi][nj][e] + bv;
        size_t idx = (size_t)row * N + col;
        if (mode == 0) {
          ((bf16_t*)Cz)[idx] = (bf16_t)v;
        } else if (mode == 1) {
          float u = v * (0.7978845608028654f + 0.0356774081f * v * v);
          float ex = EXP2F(u * 2.885390082f);
          float gel = 0.5f * v * (1.f + (ex - 1.f) / (ex + 1.f));
          ((bf16_t*)Cz)[idx] = (bf16_t)gel;
        } else {
          ((float*)Cz)[idx] = v;
        }
      }
    }
}

// ---------------- flash attention: 128q/block, operand-swapped, reg-resident P ----------------
__global__ __launch_bounds__(256) void attn_kernel(const bf16_t* __restrict__ qkv,
                                                   const bf16_t* __restrict__ vT,
                                                   bf16_t* __restrict__ ob) {
  __shared__ bf16_t smem[3 * 128 * 64];   // 48 KB: Ks | Vts | Qs
  bf16_t* Ks  = smem;
  bf16_t* Vts = smem + 8192;
  bf16_t* Qs  = smem + 16384;
  const int qt = blockIdx.x, h = blockIdx.y, b = blockIdx.z;
  const int t = threadIdx.x, lane = t & 63, w = t >> 6;
  const int l32 = lane & 31, hi = lane >> 5;
  const size_t RS = 3 * HID;
  const int bh = b * NHEAD + h;

  const bf16_t* qbase = qkv + ((size_t)(b * LSEQ + qt * 128)) * RS + h * HD;
  const bf16_t* kbase = qkv + ((size_t)b * LSEQ) * RS + HID + h * HD;
  const bf16_t* vtbase = vT + (size_t)bh * HD * LSEQ;

#pragma unroll
  for (int s = 0; s < 4; ++s) {
    int l = t + s * 256;
    int r = l >> 3, c8 = l & 7;
    gld_lds16(qbase + (size_t)r * RS + ((c8 ^ (r & 7)) * 8), Qs + l * 8);
  }
  __syncthreads();

  const float sc = 0.18033688011112042f;  // (1/sqrt(64)) * log2(e)
  bf16x8 bq[4];
  {
    int qrow = 32 * w + l32;
#pragma unroll
    for (int c = 0; c < 4; ++c) {
      int y = 2 * c + hi;
      bf16x8 q8 = *(const bf16x8*)(Qs + qrow * 64 + ((y ^ (qrow & 7)) * 8));
#pragma unroll
      for (int e = 0; e < 8; ++e) q8[e] = (bf16_t)((float)q8[e] * sc);
      bq[c] = q8;
    }
  }

  f32x16 accO[2];
#pragma unroll
  for (int dt = 0; dt < 2; ++dt)
#pragma unroll
    for (int e = 0; e < 16; ++e) accO[dt][e] = 0.f;
  float l_acc = 0.f;

  for (int kt = 0; kt < LSEQ / 128; ++kt) {
    __syncthreads();
#pragma unroll
    for (int s = 0; s < 4; ++s) {
      int l = t + s * 256;
      int r = l >> 3, c8 = l & 7;
      gld_lds16(kbase + (size_t)(kt * 128 + r) * RS + ((c8 ^ (r & 7)) * 8), Ks + l * 8);
      int rv = l >> 4, c16 = l & 15;
      gld_lds16(vtbase + (size_t)rv * LSEQ + kt * 128 + ((c16 ^ (rv & 7)) * 8), Vts + l * 8);
    }
    __syncthreads();

#pragma unroll
    for (int kt2 = 0; kt2 < 2; ++kt2) {
      f32x16 s0, s1;
#pragma unroll
      for (int e = 0; e < 16; ++e) { s0[e] = 0.f; s1[e] = 0.f; }
#pragma unroll
      for (int c = 0; c < 4; ++c) {
        int y = 2 * c + hi;
        int r0 = (2 * kt2 + 0) * 32 + l32;
        bf16x8 a0 = *(const bf16x8*)(Ks + r0 * 64 + ((y ^ (r0 & 7)) * 8));
        s0 = __builtin_amdgcn_mfma_f32_32x32x16_bf16(a0, bq[c], s0, 0, 0, 0);
        int r1 = (2 * kt2 + 1) * 32 + l32;
        bf16x8 a1 = *(const bf16x8*)(Ks + r1 * 64 + ((y ^ (r1 & 7)) * 8));
        s1 = __builtin_amdgcn_mfma_f32_32x32x16_bf16(a1, bq[c], s1, 0, 0, 0);
      }

      unsigned pf[2][2][4];
#pragma unroll
      for (int tile = 0; tile < 2; ++tile) {
        f32x16& sv = tile ? s1 : s0;
        float p[16];
#pragma unroll
        for (int e = 0; e < 16; ++e) { p[e] = EXP2F(sv[e]); l_acc += p[e]; }
        unsigned lo[4], hi_[4];
#pragma unroll
        for (int g = 0; g < 4; ++g) {
          lo[g] = pk_bf16(p[4 * g + 0], p[4 * g + 1]);
          hi_[g] = pk_bf16(p[4 * g + 2], p[4 * g + 3]);
        }
#pragma unroll
        for (int c2 = 0; c2 < 2; ++c2) {
          unsigned aL = lo[2 * c2], bL = lo[2 * c2 + 1];
          swap32(aL, bL);
          pf[tile][c2][0] = aL; pf[tile][c2][2] = bL;
          unsigned aH = hi_[2 * c2], bH = hi_[2 * c2 + 1];
          swap32(aH, bH);
          pf[tile][c2][1] = aH; pf[tile][c2][3] = bH;
        }
      }

#pragma unroll
      for (int dt = 0; dt < 2; ++dt)
#pragma unroll
        for (int tile = 0; tile < 2; ++tile)
#pragma unroll
          for (int c2 = 0; c2 < 2; ++c2) {
            int ktile = 2 * kt2 + tile;
            int c8v = ktile * 4 + c2 * 2 + hi;
            int rv = dt * 32 + l32;
            bf16x8 av = *(const bf16x8*)(Vts + rv * 128 + ((c8v ^ (rv & 7)) * 8));
            union { unsigned u[4]; bf16x8 v; } bp;
            bp.u[0] = pf[tile][c2][0]; bp.u[1] = pf[tile][c2][1];
            bp.u[2] = pf[tile][c2][2]; bp.u[3] = pf[tile][c2][3];
            accO[dt] = __builtin_amdgcn_mfma_f32_32x32x16_bf16(av, bp.v, accO[dt], 0, 0, 0);
          }
    }
  }

  l_acc += __shfl_xor(l_acc, 32, 64);
  float inv = 1.f / l_acc;

  __syncthreads();
  bf16_t* Osh = smem;
  {
    int q = 32 * w + l32;
#pragma unroll
    for (int dt = 0; dt < 2; ++dt)
#pragma unroll
      for (int e = 0; e < 16; ++e) {
        int d = dt * 32 + (e & 3) + 8 * (e >> 2) + 4 * hi;
        Osh[q * 68 + d] = (bf16_t)(accO[dt][e] * inv);
      }
  }
  __syncthreads();
#pragma unroll
  for (int s = 0; s < 4; ++s) {
    int l = t + s * 256;
    int r = l >> 3, c8 = l & 7;
    bf16x8 v = *(const bf16x8*)(Osh + r * 68 + c8 * 8);
    *(bf16x8*)(ob + ((size_t)(b * LSEQ + qt * 128 + r)) * HID + h * HD + c8 * 8) = v;
  }
}

// ---------------- residual add + LayerNorm (Y = Y0 [+ Y1]) ----------------
__global__ __launch_bounds__(256) void resid_ln(const float* __restrict__ X,
                                                const float* __restrict__ Y0,
                                                const float* __restrict__ Y1,
                                                const float* __restrict__ g,
                                                const float* __restrict__ be,
                                                float* __restrict__ outf,
                                                bf16_t* __restrict__ outb) {
  const int row = blockIdx.x;
  const int t = threadIdx.x;
  float4 a = ((const float4*)X)[(size_t)row * 256 + t];
  float4 b0 = ((const float4*)Y0)[(size_t)row * 256 + t];
  float v0 = a.x + b0.x, v1 = a.y + b0.y, v2 = a.z + b0.z, v3 = a.w + b0.w;
  if (Y1) {
    float4 b1 = ((const float4*)Y1)[(size_t)row * 256 + t];
    v0 += b1.x; v1 += b1.y; v2 += b1.z; v3 += b1.w;
  }
  float s = v0 + v1 + v2 + v3;
  float s2 = v0 * v0 + v1 * v1 + v2 * v2 + v3 * v3;
#pragma unroll
  for (int msk = 1; msk < 64; msk <<= 1) {
    s += __shfl_xor(s, msk, 64);
    s2 += __shfl_xor(s2, msk, 64);
  }
  __shared__ float red[8];
  int w = t >> 6;
  if ((t & 63) == 0) { red[w] = s; red[w + 4] = s2; }
  __syncthreads();
  s = red[0] + red[1] + red[2] + red[3];
  s2 = red[4] + red[5] + red[6] + red[7];
  float mu = s * (1.f / 1024.f);
  float var = s2 * (1.f / 1024.f) - mu * mu;
  float rstd = rsqrtf(var + 1e-5f);
  float4 gg = ((const float4*)g)[t];
  float4 bb = ((const float4*)be)[t];
  float o0 = (v0 - mu) * rstd * gg.x + bb.x;
  float o1 = (v1 - mu) * rstd * gg.y + bb.y;
  float o2 = (v2 - mu) * rstd * gg.z + bb.z;
  float o3 = (v3 - mu) * rstd * gg.w + bb.w;
  float4 o = {o0, o1, o2, o3};
  ((float4*)outf)[(size_t)row * 256 + t] = o;
  if (outb) {
    bf16x4 ob4;
    ob4[0] = (bf16_t)o0; ob4[1] = (bf16_t)o1; ob4[2] = (bf16_t)o2; ob4[3] = (bf16_t)o3;
    ((bf16x4*)outb)[(size_t)row * 256 + t] = ob4;
  }
}

// ---------------- host ----------------
extern "C" void kernel_launch(void* const* d_in, const int* in_sizes, int n_in,
                              void* d_out, int out_size, void* d_ws, size_t ws_size,
                              hipStream_t stream) {
  const float* x     = (const float*)d_in[0];
  const float* Wqkv  = (const float*)d_in[1];
  const float* bqkv  = (const float*)d_in[2];
  const float* Wproj = (const float*)d_in[3];
  const float* bproj = (const float*)d_in[4];
  const float* W1    = (const float*)d_in[5];
  const float* b1    = (const float*)d_in[6];
  const float* W2    = (const float*)d_in[7];
  const float* b2    = (const float*)d_in[8];
  const float* g1    = (const float*)d_in[9];
  const float* be1   = (const float*)d_in[10];
  const float* g2    = (const float*)d_in[11];
  const float* be2   = (const float*)d_in[12];
  float* out = (float*)d_out;

  char* ws = (char*)d_ws;
  size_t off = 0;
  auto alloc = [&](size_t bytes) -> char* {
    char* p = ws + off;
    off += (bytes + 255) & ~(size_t)255;
    return p;
  };
  bf16_t* wqkvT  = (bf16_t*)alloc((size_t)3072 * 1024 * 2);
  bf16_t* wprojT = (bf16_t*)alloc((size_t)1024 * 1024 * 2);
  bf16_t* w1T    = (bf16_t*)alloc((size_t)4096 * 1024 * 2);
  bf16_t* w2T    = (bf16_t*)alloc((size_t)1024 * 4096 * 2);
  char*   xb_ob  = alloc((size_t)MROWS * HID * 2);
  char*   qkv_ff = alloc((size_t)MROWS * EXPD * 2);
  char*   a_f2   = alloc((size_t)MROWS * HID * 4);
  float*  h      = (float*)alloc((size_t)MROWS * HID * 4);
  bf16_t* hb     = (bf16_t*)alloc((size_t)MROWS * HID * 2);
  float*  c1     = (float*)alloc((size_t)MROWS * HID * 4);  // split-K second half
  const bool sk = (off <= ws_size);  // fall back to unsplit if ws too small

  bf16_t* xb    = (bf16_t*)xb_ob;
  bf16_t* ob    = (bf16_t*)xb_ob;
  bf16_t* qkvb  = (bf16_t*)qkv_ff;
  bf16_t* ff1b  = (bf16_t*)qkv_ff;
  float*  attnf = (float*)a_f2;
  float*  ff2f  = (float*)a_f2;
  bf16_t* vTg   = hb;  // alias: vT live only qkv->attn; hb live only after LN1
  float*  y1    = sk ? c1 : nullptr;

  dim3 blk(256);
  transpose_cvt<<<dim3(3072 / 32, 1024 / 32), blk, 0, stream>>>(Wqkv, wqkvT, 1024, 3072);
  transpose_cvt<<<dim3(1024 / 32, 1024 / 32), blk, 0, stream>>>(Wproj, wprojT, 1024, 1024);
  transpose_cvt<<<dim3(4096 / 32, 1024 / 32), blk, 0, stream>>>(W1, w1T, 1024, 4096);
  transpose_cvt<<<dim3(1024 / 32, 4096 / 32), blk, 0, stream>>>(W2, w2T, 4096, 1024);
  cvt_bf16<<<MROWS * HID / 4 / 256, blk, 0, stream>>>(x, xb, MROWS * HID / 4);

  // qkv = x @ Wqkv + bqkv  (bf16 out)
  gemm_bt<<<dim3(3072 / 128, MROWS / 128, 1), blk, 0, stream>>>(
      xb, wqkvT, bqkv, qkvb, nullptr, MROWS, 3072, 1024, 1024, 0);
  transpose_v<<<dim3(LSEQ / 64, BATCH * NHEAD), blk, 0, stream>>>(qkvb, vTg);
  attn_kernel<<<dim3(LSEQ / 128, NHEAD, BATCH), blk, 0, stream>>>(qkvb, vTg, ob);
  // proj (f32 out, split-K=2 when ws allows)
  gemm_bt<<<dim3(1024 / 128, MROWS / 128, sk ? 2 : 1), blk, 0, stream>>>(
      ob, wprojT, bproj, attnf, c1, MROWS, 1024, sk ? 512 : 1024, 1024, 2);
  resid_ln<<<MROWS, blk, 0, stream>>>(x, attnf, y1, g1, be1, h, hb);
  // ff1 = gelu(h @ W1 + b1)
  gemm_bt<<<dim3(4096 / 128, MROWS / 128, 1), blk, 0, stream>>>(
      hb, w1T, b1, ff1b, nullptr, MROWS, 4096, 1024, 1024, 1);
  // ff2 = ff1 @ W2 + b2  (f32 out, split-K=2 when ws allows)
  gemm_bt<<<dim3(1024 / 128, MROWS / 128, sk ? 2 : 1), blk, 0, stream>>>(
      ff1b, w2T, b2, ff2f, c1, MROWS, 1024, sk ? 2048 : 4096, 4096, 2);
  resid_ln<<<MROWS, blk, 0, stream>>>(h, ff2f, y1, g2, be2, out, (bf16_t*)nullptr);
}